// Round 3
// baseline (723.437 us; speedup 1.0000x reference)
//
#include <hip/hip_runtime.h>

#define NE 800000
#define NN 50000
#define NG 256

typedef unsigned short us;
typedef us us8 __attribute__((ext_vector_type(8)));
typedef __bf16 bf16x8 __attribute__((ext_vector_type(8)));
typedef float f32x4 __attribute__((ext_vector_type(4)));

__device__ __forceinline__ us f2bf(float f) {
    unsigned int u = __builtin_bit_cast(unsigned int, f);
    u += 0x7fffu + ((u >> 16) & 1u);
    return (us)(u >> 16);
}
__device__ __forceinline__ f32x4 mfma16(us8 a, us8 b, f32x4 c) {
    return __builtin_amdgcn_mfma_f32_16x16x32_bf16(
        __builtin_bit_cast(bf16x8, a), __builtin_bit_cast(bf16x8, b), c, 0, 0, 0);
}
__device__ __forceinline__ us8 ld8(const us* p) { return *(const us8*)p; }
__device__ __forceinline__ us8 cvt8(const float* src) {
    f32x4 v0 = *(const f32x4*)src;
    f32x4 v1 = *(const f32x4*)(src + 4);
    us8 p;
#pragma unroll
    for (int q = 0; q < 4; ++q) { p[q] = f2bf(v0[q]); p[4 + q] = f2bf(v1[q]); }
    return p;
}

// ---------------------------------------------------------------- histograms
__global__ void count_kernel(const int* __restrict__ eidx, const int* __restrict__ batch,
                             int* __restrict__ deg, int* __restrict__ gcount) {
    int i = blockIdx.x * blockDim.x + threadIdx.x;
    int stride = gridDim.x * blockDim.x;
    for (int e = i; e < NE; e += stride) atomicAdd(&deg[eidx[NE + e]], 1);
    for (int n = i; n < NN; n += stride) atomicAdd(&gcount[batch[n]], 1);
}

// ---------------------------------------------------------------- edge + message (fused)
// per 64-edge tile: A1=[x[row]|x[col]|ea|u[batch[row]]] (K=176, pad to 192)
// G1: H1=relu(A1@e_w1+b1)  G2: edge_new=H1@e_w2+b2 (-> d_out fp32, EB bf16)
// G3: H2=relu([x[row]|edge_new]@n1_w1+b1)  G4: m=H2@n1_w2+b2 -> atomic aggsum[col]
__global__ __launch_bounds__(256, 2) void edge_kernel(
    const float* __restrict__ x, const float* __restrict__ ea, const float* __restrict__ uu,
    const float* __restrict__ e_w1, const float* __restrict__ e_b1,
    const float* __restrict__ e_w2, const float* __restrict__ e_b2,
    const float* __restrict__ n1_w1, const float* __restrict__ n1_b1,
    const float* __restrict__ n1_w2, const float* __restrict__ n1_b2,
    const int* __restrict__ eidx, const int* __restrict__ batch,
    float* __restrict__ out_e, float* __restrict__ aggsum)
{
    __shared__ us A1[64][200];   // stride 200 us = 400B -> 16B aligned rows, 2-way max alias
    __shared__ us H [64][136];
    __shared__ us EB[64][72];

    const int tid = threadIdx.x;
    const int w   = tid >> 6;
    const int l   = tid & 63;
    const int hk  = l >> 4;
    const int c16 = l & 15;

    // zero K-pad cols 176..191 once (never rewritten)
    for (int i = tid; i < 64 * 16; i += 256)
        A1[i >> 4][176 + (i & 15)] = 0;

    // ---- persistent bf16 B-fragments in VGPRs (weights are fp32 in HBM) ----
    us8 w1f[6][2], w2f[4], m1f[4][2], m2f[4][2];
#pragma unroll
    for (int kt = 0; kt < 6; ++kt)
#pragma unroll
        for (int nt = 0; nt < 2; ++nt) {
            us8 f;
#pragma unroll
            for (int i = 0; i < 8; ++i) {
                int k = kt * 32 + hk * 8 + i;
                f[i] = (k < 176) ? f2bf(e_w1[k * 128 + w * 32 + nt * 16 + c16]) : (us)0;
            }
            w1f[kt][nt] = f;
        }
#pragma unroll
    for (int kt = 0; kt < 4; ++kt) {
        us8 f;
#pragma unroll
        for (int i = 0; i < 8; ++i)
            f[i] = f2bf(e_w2[(kt * 32 + hk * 8 + i) * 64 + w * 16 + c16]);
        w2f[kt] = f;
    }
#pragma unroll
    for (int kt = 0; kt < 4; ++kt)
#pragma unroll
        for (int nt = 0; nt < 2; ++nt) {
            us8 f, g;
#pragma unroll
            for (int i = 0; i < 8; ++i) {
                int k = kt * 32 + hk * 8 + i;
                f[i] = f2bf(n1_w1[k * 128 + w * 32 + nt * 16 + c16]);
                g[i] = f2bf(n1_w2[k * 128 + w * 32 + nt * 16 + c16]);
            }
            m1f[kt][nt] = f;
            m2f[kt][nt] = g;
        }

    const float b1v0  = e_b1[w * 32 + c16];
    const float b1v1  = e_b1[w * 32 + 16 + c16];
    const float b2v   = e_b2[w * 16 + c16];
    const float nb1v0 = n1_b1[w * 32 + c16];
    const float nb1v1 = n1_b1[w * 32 + 16 + c16];
    const float nb2v0 = n1_b2[w * 32 + c16];
    const float nb2v1 = n1_b2[w * 32 + 16 + c16];

    for (int it = blockIdx.x; it < NE / 64; it += gridDim.x) {
        const int e0 = it * 64;
        // ---- stage gathered features: 22 chunks of 8 fp32 -> bf16 per edge ----
        for (int i = tid; i < 64 * 22; i += 256) {
            int e  = i / 22;
            int ch = i - e * 22;
            int ge = e0 + e;
            const float* src;
            if (ch < 8)       src = &x[(size_t)eidx[ge] * 64 + ch * 8];
            else if (ch < 16) src = &x[(size_t)eidx[NE + ge] * 64 + (ch - 8) * 8];
            else if (ch < 20) src = &ea[(size_t)ge * 32 + (ch - 16) * 8];
            else              src = &uu[(size_t)batch[eidx[ge]] * 16 + (ch - 20) * 8];
            *(us8*)&A1[e][ch * 8] = cvt8(src);
        }
        __syncthreads();

        // ---- G1: H1 = relu(A1 @ e_w1 + b1) ----
#pragma unroll
        for (int mt = 0; mt < 4; ++mt) {
            f32x4 a0 = {0.f, 0.f, 0.f, 0.f}, a1 = {0.f, 0.f, 0.f, 0.f};
#pragma unroll
            for (int kt = 0; kt < 6; ++kt) {
                us8 a = ld8(&A1[mt * 16 + c16][kt * 32 + hk * 8]);
                a0 = mfma16(a, w1f[kt][0], a0);
                a1 = mfma16(a, w1f[kt][1], a1);
            }
#pragma unroll
            for (int j = 0; j < 4; ++j) {
                int row = mt * 16 + hk * 4 + j;
                H[row][w * 32 + c16]      = f2bf(fmaxf(a0[j] + b1v0, 0.f));
                H[row][w * 32 + 16 + c16] = f2bf(fmaxf(a1[j] + b1v1, 0.f));
            }
        }
        __syncthreads();

        // ---- G2: edge_new = H1 @ e_w2 + b2 ----
#pragma unroll
        for (int mt = 0; mt < 4; ++mt) {
            f32x4 a0 = {0.f, 0.f, 0.f, 0.f};
#pragma unroll
            for (int kt = 0; kt < 4; ++kt) {
                us8 a = ld8(&H[mt * 16 + c16][kt * 32 + hk * 8]);
                a0 = mfma16(a, w2f[kt], a0);
            }
#pragma unroll
            for (int j = 0; j < 4; ++j) {
                int row = mt * 16 + hk * 4 + j;
                float val = a0[j] + b2v;
                EB[row][w * 16 + c16] = f2bf(val);
                out_e[(size_t)(e0 + row) * 64 + w * 16 + c16] = val;
            }
        }
        __syncthreads();

        // ---- G3: H2 = relu([x[row] | edge_new] @ n1_w1 + b1) ----
#pragma unroll
        for (int mt = 0; mt < 4; ++mt) {
            f32x4 a0 = {0.f, 0.f, 0.f, 0.f}, a1 = {0.f, 0.f, 0.f, 0.f};
#pragma unroll
            for (int kt = 0; kt < 4; ++kt) {
                us8 a = (kt < 2) ? ld8(&A1[mt * 16 + c16][kt * 32 + hk * 8])
                                 : ld8(&EB[mt * 16 + c16][(kt - 2) * 32 + hk * 8]);
                a0 = mfma16(a, m1f[kt][0], a0);
                a1 = mfma16(a, m1f[kt][1], a1);
            }
#pragma unroll
            for (int j = 0; j < 4; ++j) {
                int row = mt * 16 + hk * 4 + j;
                H[row][w * 32 + c16]      = f2bf(fmaxf(a0[j] + nb1v0, 0.f));
                H[row][w * 32 + 16 + c16] = f2bf(fmaxf(a1[j] + nb1v1, 0.f));
            }
        }
        __syncthreads();

        // ---- G4: m = H2 @ n1_w2 + b2 -> scatter-add to aggsum[col] ----
#pragma unroll
        for (int mt = 0; mt < 4; ++mt) {
            f32x4 a0 = {0.f, 0.f, 0.f, 0.f}, a1 = {0.f, 0.f, 0.f, 0.f};
#pragma unroll
            for (int kt = 0; kt < 4; ++kt) {
                us8 a = ld8(&H[mt * 16 + c16][kt * 32 + hk * 8]);
                a0 = mfma16(a, m2f[kt][0], a0);
                a1 = mfma16(a, m2f[kt][1], a1);
            }
#pragma unroll
            for (int j = 0; j < 4; ++j) {
                int row  = mt * 16 + hk * 4 + j;
                int node = eidx[NE + e0 + row];
                atomicAdd(&aggsum[(size_t)node * 128 + w * 32 + c16],      a0[j] + nb2v0);
                atomicAdd(&aggsum[(size_t)node * 128 + w * 32 + 16 + c16], a1[j] + nb2v1);
            }
        }
        __syncthreads();   // protect H/A1/EB before next-iter staging overwrites
    }
}

// ---------------------------------------------------------------- node update
// A3 = [x | aggsum/max(deg,1) | u[batch]]  (K=208, pad to 224)
// G5: H3 = relu(A3@n2_w1+b1)   G6: x_new = H3@n2_w2+b2 -> d_out fp32 + atomic gsum
__global__ __launch_bounds__(256, 2) void node_kernel(
    const float* __restrict__ x, const float* __restrict__ uu,
    const float* __restrict__ n2_w1, const float* __restrict__ n2_b1,
    const float* __restrict__ n2_w2, const float* __restrict__ n2_b2,
    const int* __restrict__ batch,
    const float* __restrict__ aggsum, const int* __restrict__ deg,
    float* __restrict__ out_x, float* __restrict__ gsum)
{
    __shared__ us A3[64][232];
    __shared__ us H3[64][136];

    const int tid = threadIdx.x;
    const int w   = tid >> 6;
    const int l   = tid & 63;
    const int hk  = l >> 4;
    const int c16 = l & 15;

    for (int i = tid; i < 64 * 16; i += 256)
        A3[i >> 4][208 + (i & 15)] = 0;

    us8 w1f[7][2], w2f[4];
#pragma unroll
    for (int kt = 0; kt < 7; ++kt)
#pragma unroll
        for (int nt = 0; nt < 2; ++nt) {
            us8 f;
#pragma unroll
            for (int i = 0; i < 8; ++i) {
                int k = kt * 32 + hk * 8 + i;
                f[i] = (k < 208) ? f2bf(n2_w1[k * 128 + w * 32 + nt * 16 + c16]) : (us)0;
            }
            w1f[kt][nt] = f;
        }
#pragma unroll
    for (int kt = 0; kt < 4; ++kt) {
        us8 f;
#pragma unroll
        for (int i = 0; i < 8; ++i)
            f[i] = f2bf(n2_w2[(kt * 32 + hk * 8 + i) * 64 + w * 16 + c16]);
        w2f[kt] = f;
    }
    const float b1v0 = n2_b1[w * 32 + c16];
    const float b1v1 = n2_b1[w * 32 + 16 + c16];
    const float b2v  = n2_b2[w * 16 + c16];

    const int niter = (NN + 63) / 64;
    for (int it = blockIdx.x; it < niter; it += gridDim.x) {
        const int n0 = it * 64;
        for (int i = tid; i < 64 * 26; i += 256) {
            int n  = i / 26;
            int ch = i - n * 26;
            int gn = n0 + n;
            us8 v = {0, 0, 0, 0, 0, 0, 0, 0};
            if (gn < NN) {
                if (ch < 8) {
                    v = cvt8(&x[(size_t)gn * 64 + ch * 8]);
                } else if (ch < 24) {
                    int cc = (ch - 8) * 8;
                    float inv = 1.0f / fmaxf((float)deg[gn], 1.0f);
                    const float* ap = &aggsum[(size_t)gn * 128 + cc];
                    us8 t;
#pragma unroll
                    for (int q = 0; q < 8; ++q) t[q] = f2bf(ap[q] * inv);
                    v = t;
                } else {
                    v = cvt8(&uu[(size_t)batch[gn] * 16 + (ch - 24) * 8]);
                }
            }
            *(us8*)&A3[n][ch * 8] = v;
        }
        __syncthreads();

        // G5
#pragma unroll
        for (int mt = 0; mt < 4; ++mt) {
            f32x4 a0 = {0.f, 0.f, 0.f, 0.f}, a1 = {0.f, 0.f, 0.f, 0.f};
#pragma unroll
            for (int kt = 0; kt < 7; ++kt) {
                us8 a = ld8(&A3[mt * 16 + c16][kt * 32 + hk * 8]);
                a0 = mfma16(a, w1f[kt][0], a0);
                a1 = mfma16(a, w1f[kt][1], a1);
            }
#pragma unroll
            for (int j = 0; j < 4; ++j) {
                int row = mt * 16 + hk * 4 + j;
                H3[row][w * 32 + c16]      = f2bf(fmaxf(a0[j] + b1v0, 0.f));
                H3[row][w * 32 + 16 + c16] = f2bf(fmaxf(a1[j] + b1v1, 0.f));
            }
        }
        __syncthreads();

        // G6
#pragma unroll
        for (int mt = 0; mt < 4; ++mt) {
            f32x4 a0 = {0.f, 0.f, 0.f, 0.f};
#pragma unroll
            for (int kt = 0; kt < 4; ++kt) {
                us8 a = ld8(&H3[mt * 16 + c16][kt * 32 + hk * 8]);
                a0 = mfma16(a, w2f[kt], a0);
            }
#pragma unroll
            for (int j = 0; j < 4; ++j) {
                int row = mt * 16 + hk * 4 + j;
                int gn  = n0 + row;
                if (gn < NN) {
                    float val = a0[j] + b2v;
                    out_x[(size_t)gn * 64 + w * 16 + c16] = val;
                    atomicAdd(&gsum[batch[gn] * 64 + w * 16 + c16], val);
                }
            }
        }
        __syncthreads();   // protect H3/A3 before next-iter staging
    }
}

// ---------------------------------------------------------------- global update (full fp32)
__global__ void global_kernel(const float* __restrict__ uu,
                              const float* __restrict__ g_w1, const float* __restrict__ g_b1,
                              const float* __restrict__ g_w2, const float* __restrict__ g_b2,
                              const float* __restrict__ gsum, const int* __restrict__ gcount,
                              float* __restrict__ out_u)
{
    const int g = blockIdx.x;
    const int t = threadIdx.x;
    __shared__ float gin[80];
    __shared__ float h[128];
    if (t < 16) gin[t] = uu[g * 16 + t];
    else if (t < 80) {
        float c = fmaxf((float)gcount[g], 1.0f);
        gin[t] = gsum[g * 64 + (t - 16)] / c;
    }
    __syncthreads();
    float a = g_b1[t];
    for (int k = 0; k < 80; ++k) a += gin[k] * g_w1[k * 128 + t];
    h[t] = fmaxf(a, 0.f);
    __syncthreads();
    if (t < 32) {
        float a2 = g_b2[t];
        for (int k = 0; k < 128; ++k) a2 += h[k] * g_w2[k * 32 + t];
        out_u[g * 32 + t] = a2;
    }
}

extern "C" void kernel_launch(void* const* d_in, const int* in_sizes, int n_in,
                              void* d_out, int out_size, void* d_ws, size_t ws_size,
                              hipStream_t stream)
{
    const float* x     = (const float*)d_in[0];
    const float* ea    = (const float*)d_in[1];
    const float* uu    = (const float*)d_in[2];
    const float* e_w1  = (const float*)d_in[3];
    const float* e_b1  = (const float*)d_in[4];
    const float* e_w2  = (const float*)d_in[5];
    const float* e_b2  = (const float*)d_in[6];
    const float* n1_w1 = (const float*)d_in[7];
    const float* n1_b1 = (const float*)d_in[8];
    const float* n1_w2 = (const float*)d_in[9];
    const float* n1_b2 = (const float*)d_in[10];
    const float* n2_w1 = (const float*)d_in[11];
    const float* n2_b1 = (const float*)d_in[12];
    const float* n2_w2 = (const float*)d_in[13];
    const float* n2_b2 = (const float*)d_in[14];
    const float* g_w1  = (const float*)d_in[15];
    const float* g_b1  = (const float*)d_in[16];
    const float* g_w2  = (const float*)d_in[17];
    const float* g_b2  = (const float*)d_in[18];
    const int* eidx  = (const int*)d_in[19];
    const int* batch = (const int*)d_in[20];

    float* out_x = (float*)d_out;
    float* out_e = out_x + (size_t)NN * 64;
    float* out_u = out_e + (size_t)NE * 64;

    float* aggsum = (float*)d_ws;
    float* gsum   = aggsum + (size_t)NN * 128;
    int*   deg    = (int*)(gsum + (size_t)NG * 64);
    int*   gcount = deg + NN;
    size_t used = ((size_t)NN * 128 + (size_t)NG * 64) * sizeof(float) + (NN + NG) * sizeof(int);

    hipMemsetAsync(d_ws, 0, used, stream);
    hipLaunchKernelGGL(count_kernel, dim3(512), dim3(256), 0, stream, eidx, batch, deg, gcount);
    hipLaunchKernelGGL(edge_kernel, dim3(1024), dim3(256), 0, stream,
        x, ea, uu, e_w1, e_b1, e_w2, e_b2, n1_w1, n1_b1, n1_w2, n1_b2,
        eidx, batch, out_e, aggsum);
    hipLaunchKernelGGL(node_kernel, dim3(782), dim3(256), 0, stream,
        x, uu, n2_w1, n2_b1, n2_w2, n2_b2, batch, aggsum, deg, out_x, gsum);
    hipLaunchKernelGGL(global_kernel, dim3(NG), dim3(128), 0, stream,
        uu, g_w1, g_b1, g_w2, g_b2, gsum, gcount, out_u);
}